// Round 5
// baseline (69.960 us; speedup 1.0000x reference)
//
#include <hip/hip_runtime.h>

// =====================================================================
// VeroneseDecoding: out[:, 0:4] = top-eigenvector(sym4x4(z[:, :10])) (sign-fixed)
//                   out[:, 4:132] = relu(z @ W1 + b1) @ W2 + b2
// Inputs (f32): z[65536,256], W1[256,1024], b1[1024], W2[1024,128], b2[128]
// Output (f32): [65536,132]
// =====================================================================

typedef short s16x8 __attribute__((ext_vector_type(8)));   // 8 bf16 (4 VGPRs)
typedef float f32x4 __attribute__((ext_vector_type(4)));
typedef unsigned char u8;

__device__ __forceinline__ f32x4 mfma16(s16x8 a, s16x8 b, f32x4 c) {
    return __builtin_amdgcn_mfma_f32_16x16x32_bf16(a, b, c, 0, 0, 0);
}

// manual RNE f32 -> bf16 bits (prep kernel only; off critical path)
__device__ __forceinline__ short f2bf(float f) {
    unsigned int u = __float_as_uint(f);
    u = (u + 0x7fffu + ((u >> 16) & 1u)) >> 16;
    return (short)u;
}

// packed RNE convert: 2 f32 -> 1 dword of 2 bf16
__device__ __forceinline__ unsigned cvt_pk(float lo, float hi) {
    unsigned r;
    asm("v_cvt_pk_bf16_f32 %0, %1, %2" : "=v"(r) : "v"(lo), "v"(hi));
    return r;
}

// async global->LDS, 16B per lane. Dest must be wave-uniform base + lane*16.
__device__ __forceinline__ void gload_lds16(const void* g, void* l) {
    __builtin_amdgcn_global_load_lds(
        (const __attribute__((address_space(1))) unsigned int*)g,
        (__attribute__((address_space(3))) unsigned int*)l, 16, 0, 0);
}

// ---------------------------------------------------------------------
// prep: W1^T / W2^T -> bf16 fragment-major for 32-col chunks.
//   w1t unit f = ((c*2+ct)*8+s)*64 + lane   (c<32, ct<2, s<8)
//     holds W1[k = s*32+q*8+j][n1 = c*32+ct*16+r16], j=0..7
//   w2t unit f = (c*8+ct2)*64 + lane        (c<32, ct2<8)
//     holds W2[k2 = c*32+q*8+j][n2 = ct2*16+r16]
// ---------------------------------------------------------------------
__global__ __launch_bounds__(256) void prep_weights(
    const float* __restrict__ W1, const float* __restrict__ W2,
    uint4* __restrict__ w1t, uint4* __restrict__ w2t)
{
    int tid = blockIdx.x * 256 + threadIdx.x;
    int q = (tid >> 4) & 3, r16 = tid & 15;
    union { short b[8]; uint4 v; } pk;
    if (tid < 32768) {                       // 32768 units = 512KB
        int s  = (tid >> 6) & 7;
        int ct = (tid >> 9) & 1;
        int c  = tid >> 10;
        int k0 = s * 32 + q * 8;
        int n1 = c * 32 + ct * 16 + r16;
        #pragma unroll
        for (int j = 0; j < 8; ++j)
            pk.b[j] = f2bf(W1[(k0 + j) * 1024 + n1]);
        w1t[tid] = pk.v;
    } else {                                 // 16384 units = 256KB
        int f   = tid - 32768;
        int ct2 = (f >> 6) & 7;
        int c   = f >> 9;
        int k0  = c * 32 + q * 8;
        int n2  = ct2 * 16 + r16;
        #pragma unroll
        for (int j = 0; j < 8; ++j)
            pk.b[j] = f2bf(W2[(k0 + j) * 128 + n2]);
        w2t[f] = pk.v;
    }
}

// ---------------------------------------------------------------------
// fused kernel: BM=128 rows/block, 256 threads = 4 waves x 32 rows,
// grid 512 -> 2 blocks/CU (LDS 60KB). 32 chunks of 32 n1-cols, double-
// buffered staging (issue c+1 before computing c). All LDS reads dense.
// LDS: bs1 2x16KB | bs2 2x8KB | h 4x2KB | bias 4KB = 60KB
// ---------------------------------------------------------------------
__global__ __launch_bounds__(256, 2) void fused_all(
    const float* __restrict__ z, const float* __restrict__ b1,
    const float* __restrict__ b2, const uint4* __restrict__ w1t,
    const uint4* __restrict__ w2t, float* __restrict__ out)
{
    __shared__ __align__(16) u8 lds[61440];
    // [0,32768): bs1 (2 x 16KB)   [32768,49152): bs2 (2 x 8KB)
    // [49152,57344): h (4 waves x 2KB)   [57344,61440): b1 f32

    const int t    = threadIdx.x;
    const int lane = t & 63;
    const int w    = t >> 6;        // wave 0..3
    const int q    = lane >> 4;     // 0..3
    const int r16  = lane & 15;
    const int bm0  = blockIdx.x * 128;
    const int rowbase = bm0 + w * 32;

    // ---------------- issue stage of chunk 0 + bias (async) ------------
    #pragma unroll
    for (int i = 0; i < 4; ++i) {
        int f = i * 256 + t;
        gload_lds16(w1t + f, lds + f * 16);
    }
    #pragma unroll
    for (int i = 0; i < 2; ++i) {
        int f = i * 256 + t;
        gload_lds16(w2t + f, lds + 32768 + f * 16);
    }
    gload_lds16(b1 + t * 4, lds + 57344 + t * 16);

    // ---------------- eig (lanes 0..31: this wave's 32 rows) ------------
    if (lane < 32) {
        int row = rowbase + lane;
        const float* zr = z + (size_t)row * 256;
        float4 v0 = *(const float4*)(zr);
        float4 v1 = *(const float4*)(zr + 4);
        float2 v2 = *(const float2*)(zr + 8);

        float A[4][4] = {{v0.x, v0.y, v0.z, v0.w},
                         {v0.y, v1.x, v1.y, v1.z},
                         {v0.z, v1.y, v1.w, v2.x},
                         {v0.w, v1.z, v2.x, v2.y}};
        float V[4][4] = {{1.f, 0.f, 0.f, 0.f},
                         {0.f, 1.f, 0.f, 0.f},
                         {0.f, 0.f, 1.f, 0.f},
                         {0.f, 0.f, 0.f, 1.f}};

#define ROT(p, qq) do {                                                   \
        float apq  = A[p][qq];                                            \
        float tau  = (A[qq][qq] - A[p][p]) *                              \
                     __builtin_amdgcn_rcpf(2.0f * apq);                   \
        float tt   = __builtin_amdgcn_rcpf(                               \
                        fabsf(tau) +                                      \
                        __builtin_amdgcn_sqrtf(fmaf(tau, tau, 1.0f)));    \
        tt = copysignf(tt, tau);                                          \
        tt = (fabsf(apq) > 1e-20f) ? tt : 0.0f;                           \
        float cth = __builtin_amdgcn_rsqf(fmaf(tt, tt, 1.0f));            \
        float sth = tt * cth;                                             \
        _Pragma("unroll")                                                 \
        for (int k = 0; k < 4; ++k) {                                     \
            float akp = A[k][p], akq = A[k][qq];                          \
            A[k][p]  = cth * akp - sth * akq;                             \
            A[k][qq] = sth * akp + cth * akq;                             \
        }                                                                 \
        _Pragma("unroll")                                                 \
        for (int k = 0; k < 4; ++k) {                                     \
            float apk = A[p][k], aqk = A[qq][k];                          \
            A[p][k]  = cth * apk - sth * aqk;                             \
            A[qq][k] = sth * apk + cth * aqk;                             \
        }                                                                 \
        _Pragma("unroll")                                                 \
        for (int k = 0; k < 4; ++k) {                                     \
            float vkp = V[k][p], vkq = V[k][qq];                          \
            V[k][p]  = cth * vkp - sth * vkq;                             \
            V[k][qq] = sth * vkp + cth * vkq;                             \
        }                                                                 \
    } while (0)

        #pragma unroll 1
        for (int sweep = 0; sweep < 6; ++sweep) {
            ROT(0, 1); ROT(0, 2); ROT(0, 3); ROT(1, 2); ROT(1, 3); ROT(2, 3);
        }
#undef ROT

        float bv = A[0][0];
        float q0 = V[0][0], q1 = V[1][0], q2 = V[2][0], q3 = V[3][0];
        #pragma unroll
        for (int k = 1; k < 4; ++k) {
            bool better = A[k][k] > bv;
            bv = better ? A[k][k] : bv;
            q0 = better ? V[0][k] : q0;
            q1 = better ? V[1][k] : q1;
            q2 = better ? V[2][k] : q2;
            q3 = better ? V[3][k] : q3;
        }
        float sgn = (q0 + 1e-9f) >= 0.0f ? 1.0f : -1.0f;
        *(float4*)(out + (size_t)row * 132) =
            make_float4(sgn * q0, sgn * q1, sgn * q2, sgn * q3);
    }

    // ---------------- persistent z B-fragments (cvt_pk packed) ----------
    // zf[mr][s] = z[rowbase + mr*16 + r16][s*32 + q*8 .. +8)
    const f32x4 zero4 = {0.f, 0.f, 0.f, 0.f};
    s16x8 zf[2][8];
    #pragma unroll
    for (int mr = 0; mr < 2; ++mr) {
        const float* zp = z + (size_t)(rowbase + mr * 16 + r16) * 256 + q * 8;
        #pragma unroll
        for (int s = 0; s < 8; ++s) {
            const float4* p = (const float4*)(zp + s * 32);
            float4 a0 = p[0], a1 = p[1];
            union { unsigned u[4]; s16x8 v; } pk;
            pk.u[0] = cvt_pk(a0.x, a0.y);
            pk.u[1] = cvt_pk(a0.z, a0.w);
            pk.u[2] = cvt_pk(a1.x, a1.y);
            pk.u[3] = cvt_pk(a1.z, a1.w);
            zf[mr][s] = pk.v;
        }
    }

    f32x4 acc2[2][8];
    #pragma unroll
    for (int mr = 0; mr < 2; ++mr)
        #pragma unroll
        for (int n = 0; n < 8; ++n) acc2[mr][n] = zero4;

    __syncthreads();   // chunk-0 staging + bias landed

    // thread-constant LDS base pointers
    const u8* const aW0 = lds + lane * 16;            // bs1 buf0
    const u8* const aW1 = lds + 16384 + lane * 16;    // bs1 buf1
    const u8* const bW0 = lds + 32768 + lane * 16;    // bs2 buf0
    const u8* const bW1 = lds + 40960 + lane * 16;    // bs2 buf1
    u8* const hwv = lds + 49152 + w * 2048;           // wave-private h (2KB)
    const int e6  = r16 & 6;
    // h-write bases (8B slot per ct,mr): unit (ct*4+q)^e6, row r16
    u8* const hw_ct0 = hwv + r16 * 64 + ((q ^ e6) << 3);
    u8* const hw_ct1 = hwv + r16 * 64 + (((4 + q) ^ e6) << 3);
    // h-read base (16B at unit pair (q*2)^e6): row r16
    const u8* const hrd = hwv + r16 * 64 + (((q * 2) ^ e6) << 3);
    const u8* const blsp = lds + 57344 + q * 16;

    auto chunk = [&](int c, const u8* a, const u8* bW,
                     u8* s1dst, u8* s2dst) {
        // ---- issue stage of chunk c+1 into the other buffer ----
        if (c < 31) {
            const uint4* s1 = w1t + (c + 1) * 1024;
            const uint4* s2 = w2t + (c + 1) * 512;
            #pragma unroll
            for (int i = 0; i < 4; ++i) {
                int f = i * 256 + t;
                gload_lds16(s1 + f, s1dst + f * 16);
            }
            #pragma unroll
            for (int i = 0; i < 2; ++i) {
                int f = i * 256 + t;
                gload_lds16(s2 + f, s2dst + f * 16);
            }
        }

        __builtin_amdgcn_s_setprio(1);

        // ---- GEMM1 (swapped): D[n1][m]; h-pack via cvt_pk; b64 write ----
        #pragma unroll
        for (int ct = 0; ct < 2; ++ct) {
            f32x4 a0 = zero4, a1 = zero4;
            #pragma unroll
            for (int s = 0; s < 8; ++s) {
                s16x8 afr = *(const s16x8*)(a + (ct * 8 + s) * 1024);
                a0 = mfma16(afr, zf[0][s], a0);
                a1 = mfma16(afr, zf[1][s], a1);
            }
            f32x4 bv = *(const f32x4*)(blsp + c * 128 + ct * 64);
            u8* const hwp = ct ? hw_ct1 : hw_ct0;
            #pragma unroll
            for (int mr = 0; mr < 2; ++mr) {
                f32x4 av = mr ? a1 : a0;
                uint2 hp;
                hp.x = cvt_pk(fmaxf(av[0] + bv[0], 0.f),
                              fmaxf(av[1] + bv[1], 0.f));
                hp.y = cvt_pk(fmaxf(av[2] + bv[2], 0.f),
                              fmaxf(av[3] + bv[3], 0.f));
                *(uint2*)(hwp + mr * 1024) = hp;
            }
        }

        // ---- GEMM2 partial (h wave-private: no barrier) ----
        {
            s16x8 af0 = *(const s16x8*)(hrd);
            s16x8 af1 = *(const s16x8*)(hrd + 1024);
            #pragma unroll
            for (int ct2 = 0; ct2 < 8; ++ct2) {
                s16x8 bfr = *(const s16x8*)(bW + ct2 * 1024);
                acc2[0][ct2] = mfma16(af0, bfr, acc2[0][ct2]);
                acc2[1][ct2] = mfma16(af1, bfr, acc2[1][ct2]);
            }
        }

        __builtin_amdgcn_s_setprio(0);

        __syncthreads();   // next-chunk staging landed; buffers swap
    };

    u8* const s1b0 = lds;
    u8* const s1b1 = lds + 16384;
    u8* const s2b0 = lds + 32768;
    u8* const s2b1 = lds + 40960;

    #pragma unroll 1
    for (int cc = 0; cc < 16; ++cc) {
        chunk(2 * cc,     aW0, bW0, s1b1, s2b1);
        chunk(2 * cc + 1, aW1, bW1, s1b0, s2b0);
    }

    // ---- epilogue: out[:, 4 + n2] = acc2 + b2 ----
    #pragma unroll
    for (int ct2 = 0; ct2 < 8; ++ct2) {
        const float b2v = b2[ct2 * 16 + r16];
        #pragma unroll
        for (int mr = 0; mr < 2; ++mr) {
            #pragma unroll
            for (int r = 0; r < 4; ++r) {
                int m = w * 32 + mr * 16 + q * 4 + r;
                out[(size_t)(bm0 + m) * 132 + 4 + ct2 * 16 + r16] =
                    acc2[mr][ct2][r] + b2v;
            }
        }
    }
}

// ---------------------------------------------------------------------
extern "C" void kernel_launch(void* const* d_in, const int* in_sizes, int n_in,
                              void* d_out, int out_size, void* d_ws, size_t ws_size,
                              hipStream_t stream) {
    const float* z  = (const float*)d_in[0];
    const float* W1 = (const float*)d_in[1];
    const float* b1 = (const float*)d_in[2];
    const float* W2 = (const float*)d_in[3];
    const float* b2 = (const float*)d_in[4];
    float* out = (float*)d_out;

    // ws layout: [0, 512KB) W1^T frag-major, [512KB, 768KB) W2^T frag-major
    uint4* w1t = (uint4*)d_ws;
    uint4* w2t = (uint4*)((char*)d_ws + 512 * 1024);

    hipLaunchKernelGGL(prep_weights, dim3(192), dim3(256), 0, stream,
                       W1, W2, w1t, w2t);
    hipLaunchKernelGGL(fused_all, dim3(512), dim3(256), 0, stream,
                       z, b1, b2, (const uint4*)w1t, (const uint4*)w2t, out);
}